// Round 8
// baseline (839.455 us; speedup 1.0000x reference)
//
#include <hip/hip_runtime.h>

#define GN   128      // graphs
#define GP   256      // nodes per graph
#define NN   32768    // total nodes
#define NEDGE 262144  // total edges
#define WALKN 20

typedef __attribute__((ext_vector_type(8))) short bfrag;   // 8 bf16 (4 VGPRs)
typedef __attribute__((ext_vector_type(4))) float ffrag;   // 4 fp32 acc

__device__ __forceinline__ ushort f2b(float f){
  unsigned u = __float_as_uint(f);
  u += 0x7fffu + ((u >> 16) & 1u);      // RNE
  return (ushort)(u >> 16);
}
__device__ __forceinline__ float b2f(ushort u){
  return __uint_as_float(((unsigned)u) << 16);
}
__device__ __forceinline__ unsigned addpair(unsigned a, unsigned b){
  float alo = __uint_as_float(a << 16), ahi = __uint_as_float(a & 0xffff0000u);
  float blo = __uint_as_float(b << 16), bhi = __uint_as_float(b & 0xffff0000u);
  return ((unsigned)f2b(ahi + bhi) << 16) | (unsigned)f2b(alo + blo);
}

// ============================================================
// build A (dense counts) + pack {src, ea[0..10]} per dst (48B, 32 slots)
// ============================================================
__global__ __launch_bounds__(256) void build_pack(const int* __restrict__ ei, const float* __restrict__ ea,
                                                  float* __restrict__ A, int* __restrict__ Ecnt,
                                                  float* __restrict__ pk){
  int e = blockIdx.x*256 + threadIdx.x;
  int s = ei[e], d = ei[NEDGE + e];
  int g = s >> 8;
  atomicAdd(&A[((size_t)g<<16) + ((size_t)(s&255)<<8) + (size_t)(d&255)], 1.0f);
  int pos = atomicAdd(&Ecnt[d], 1);
  if (pos < 32){
    float* dst = pk + ((size_t)d*32 + pos)*12;
    dst[0] = __int_as_float(s);
    const float* src = ea + (size_t)e*11;
    #pragma unroll
    for (int t = 0; t < 11; t++) dst[1+t] = src[t];
  }
}

// fused: self-loops + out-degree + dense bf16 M[c][r] = A[r][c]/deg[r]
__global__ __launch_bounds__(256) void prep_m2(float* __restrict__ A, ushort* __restrict__ Mbf){
  __shared__ float As[64][65];
  __shared__ float Bs[64][65];
  __shared__ float invd[256];
  int g = blockIdx.x;
  float* Ag = A + ((size_t)g<<16);
  int tid = threadIdx.x, tx = tid & 63, ty = tid >> 6;
  {
    float* row = Ag + ((size_t)tid<<8);
    row[tid] += 1.0f;                       // self loop
    float s = 0.f;
    for (int c = 0; c < 256; c += 4){
      float4 v = *(const float4*)&row[c];
      s += v.x + v.y + v.z + v.w;
    }
    invd[tid] = 1.f / fmaxf(s, 1.0f);
  }
  ushort* Mg = Mbf + ((size_t)g<<16);
  const int pr[10] = {0,0,0,0,1,1,1,2,2,3};
  const int pc[10] = {0,1,2,3,1,2,3,2,3,3};
  for (int t = 0; t < 10; t++){
    int R0 = pr[t]*64, C0 = pc[t]*64;
    __syncthreads();
    #pragma unroll
    for (int i = 0; i < 16; i++){
      As[ty + i*4][tx] = Ag[(size_t)(R0 + ty + i*4)*256 + C0 + tx];
      Bs[ty + i*4][tx] = Ag[(size_t)(C0 + ty + i*4)*256 + R0 + tx];
    }
    __syncthreads();
    #pragma unroll
    for (int i = 0; i < 16; i++){
      int cl = ty + i*4;
      Mg[(size_t)(C0+cl)*256 + R0+tx] = f2b(As[tx][cl] * invd[R0+tx]);
      if (R0 != C0)
        Mg[(size_t)(R0+cl)*256 + C0+tx] = f2b(Bs[tx][cl] * invd[C0+tx]);
    }
  }
}

// ============================================================
// ALL 20 walk steps in one kernel. 512-thread block owns a 128-col slice
// (Pt 67.6 KB LDS, 2 blocks/CU = 16 waves/CU); M read once per block/step.
// ============================================================
__global__ __launch_bounds__(512, 4) void rwse_mf(const ushort* __restrict__ Mbf,
                                                  float* __restrict__ pe){
  __shared__ __align__(16) ushort Pt[128*264];   // [col][row], 67.6 KB
  int bid = blockIdx.x;                          // 256 blocks
  int g  = (bid & 7)*16 + (bid >> 4);            // XCD-local graph grouping
  int cb = ((bid >> 3) & 1) << 7;
  int tid = threadIdx.x, lane = tid & 63, w = tid >> 6;
  int l15 = lane & 15, quad = lane >> 4;
  const ushort* Mg = Mbf + ((size_t)g << 16);
  uint4 z4; z4.x = z4.y = z4.z = z4.w = 0u;
  for (int i = tid; i < 4224; i += 512) reinterpret_cast<uint4*>(Pt)[i] = z4;
  __syncthreads();
  if (tid < 128) Pt[tid*264 + cb + tid] = 0x3F80;   // 1.0bf16
  __syncthreads();

  for (int s = 0; s < WALKN; s++){
    ffrag acc[2][8];
    #pragma unroll
    for (int mi = 0; mi < 2; mi++)
      #pragma unroll
      for (int n = 0; n < 8; n++) acc[mi][n] = (ffrag){0.f,0.f,0.f,0.f};
    for (int k0 = 0; k0 < 256; k0 += 32){
      bfrag a[2], b[8];
      #pragma unroll
      for (int mi = 0; mi < 2; mi++)
        a[mi] = *reinterpret_cast<const bfrag*>(&Mg[(size_t)(w*32 + mi*16 + l15)*256 + k0 + quad*8]);
      #pragma unroll
      for (int n = 0; n < 8; n++)
        b[n] = *reinterpret_cast<const bfrag*>(&Pt[(n*16 + l15)*264 + k0 + quad*8]);
      #pragma unroll
      for (int mi = 0; mi < 2; mi++)
        #pragma unroll
        for (int n = 0; n < 8; n++)
          acc[mi][n] = __builtin_amdgcn_mfma_f32_16x16x32_bf16(a[mi], b[n], acc[mi][n], 0, 0, 0);
    }
    __syncthreads();                  // all reads of Pt done
    #pragma unroll
    for (int mi = 0; mi < 2; mi++){
      int rbase = w*32 + mi*16 + quad*4;
      #pragma unroll
      for (int n = 0; n < 8; n++){
        int cl = n*16 + l15;
        int dd = cb + cl - rbase;
        if (dd >= 0 && dd < 4){       // fp32 diag before rounding
          float dv = (dd==0)?acc[mi][n][0]:(dd==1)?acc[mi][n][1]:(dd==2)?acc[mi][n][2]:acc[mi][n][3];
          pe[(size_t)((g<<8) + cb + cl)*WALKN + s] = dv;
        }
        ushort4 pkk;
        pkk.x = f2b(acc[mi][n][0]); pkk.y = f2b(acc[mi][n][1]);
        pkk.z = f2b(acc[mi][n][2]); pkk.w = f2b(acc[mi][n][3]);
        *reinterpret_cast<ushort4*>(&Pt[cl*264 + rbase]) = pkk;
      }
    }
    __syncthreads();                  // writes visible before next step
  }
}

// ============================================================
// prep: all weights -> bf16 transposed [N][Kp] (B-operand layout)
// ============================================================
__global__ __launch_bounds__(256) void prep_wt(const float* __restrict__ in_W, const float* __restrict__ g1_W,
                                               const float* __restrict__ g2_W, const float* __restrict__ qkv_W,
                                               const float* __restrict__ o_W, const float* __restrict__ m1_W,
                                               const float* __restrict__ m2_W, ushort* __restrict__ wt){
  int rgn = blockIdx.y;
  const float* src; int K, N, Kp; size_t dst;
  if (rgn == 0){ src = in_W; K=50; N=128; Kp=64; dst = 0; }
  else if (rgn <= 3){ int i=rgn-1;  src = g1_W + (size_t)i*16384; K=128; N=128; Kp=128; dst = 8192   + (size_t)i*16384; }
  else if (rgn <= 6){ int i=rgn-4;  src = g2_W + (size_t)i*16384; K=128; N=128; Kp=128; dst = 57344  + (size_t)i*16384; }
  else if (rgn <= 9){ int i=rgn-7;  src = qkv_W+ (size_t)i*49152; K=128; N=384; Kp=128; dst = 106496 + (size_t)i*49152; }
  else if (rgn <= 12){ int i=rgn-10; src = o_W  + (size_t)i*16384; K=128; N=128; Kp=128; dst = 253952 + (size_t)i*16384; }
  else if (rgn <= 15){ int i=rgn-13; src = m1_W + (size_t)i*32768; K=128; N=256; Kp=128; dst = 303104 + (size_t)i*32768; }
  else               { int i=rgn-16; src = m2_W + (size_t)i*32768; K=256; N=128; Kp=256; dst = 401408 + (size_t)i*32768; }
  int sz = N * Kp;
  int idx = blockIdx.x*256 + threadIdx.x;
  if (idx >= sz) return;
  int n = idx / Kp, kp = idx - n*Kp;
  float v = (kp < K) ? src[(size_t)kp*N + n] : 0.f;
  wt[dst + idx] = f2b(v);
}

// ============================================================
// input proj with fused concat: h = [x|pe|0] @ inW + b   (bf16 out)
// ============================================================
__global__ __launch_bounds__(256, 2) void gemm_in(
    const float* __restrict__ x, const float* __restrict__ pe,
    const ushort* __restrict__ WT, const float* __restrict__ bias,
    ushort* __restrict__ Y)
{
  __shared__ ushort XA[64 * 72];
  __shared__ ushort WS[128 * 72];
  int row0 = blockIdx.x * 64;
  int tid = threadIdx.x;
  int lane = tid & 63, wave = tid >> 6;
  int l15 = lane & 15, quad = lane >> 4;
  int wr = wave >> 1, wc = wave & 1;

  #pragma unroll
  for (int it = 0; it < 16; it++){
    int idx = tid + it*256;            // 4096 = 64 rows x 64 cols
    int r = idx >> 6, c = idx & 63;
    float v = 0.f;
    if (c < 30) v = x[(size_t)(row0+r)*30 + c];
    else if (c < 50) v = pe[(size_t)(row0+r)*20 + (c-30)];
    XA[r*72 + c] = f2b(v);
  }
  #pragma unroll
  for (int it = 0; it < 4; it++){
    int idx = tid + it*256;            // 1024 = 128 n x 8 chunks
    int n = idx >> 3, c8 = (idx & 7)*8;
    *reinterpret_cast<uint4*>(&WS[n*72 + c8]) =
        *reinterpret_cast<const uint4*>(&WT[(size_t)n*64 + c8]);
  }
  __syncthreads();
  ffrag acc[2][4];
  #pragma unroll
  for (int m = 0; m < 2; m++)
    #pragma unroll
    for (int n = 0; n < 4; n++) acc[m][n] = (ffrag){0.f,0.f,0.f,0.f};
  #pragma unroll
  for (int ks = 0; ks < 2; ks++){
    bfrag a[2], b[4];
    #pragma unroll
    for (int m = 0; m < 2; m++)
      a[m] = *reinterpret_cast<const bfrag*>(&XA[(32*wr + 16*m + l15)*72 + ks*32 + quad*8]);
    #pragma unroll
    for (int n = 0; n < 4; n++)
      b[n] = *reinterpret_cast<const bfrag*>(&WS[(64*wc + 16*n + l15)*72 + ks*32 + quad*8]);
    #pragma unroll
    for (int m = 0; m < 2; m++)
      #pragma unroll
      for (int n = 0; n < 4; n++)
        acc[m][n] = __builtin_amdgcn_mfma_f32_16x16x32_bf16(a[m], b[n], acc[m][n], 0, 0, 0);
  }
  #pragma unroll
  for (int m = 0; m < 2; m++)
    #pragma unroll
    for (int n = 0; n < 4; n++){
      int col = 64*wc + 16*n + l15;
      float bs = bias[col];
      #pragma unroll
      for (int rg = 0; rg < 4; rg++){
        int r = row0 + 32*wr + 16*m + quad*4 + rg;
        Y[(size_t)r*128 + col] = f2b(acc[m][n][rg] + bs);
      }
    }
}

// ============================================================
// plain bf16 GEMM (bias only): Y[bf16] = X[bf16] @ W + b
// ============================================================
template<int CINP>
__global__ __launch_bounds__(256, 2) void gemm_b(
    const ushort* __restrict__ X1, const ushort* __restrict__ WT,
    const float* __restrict__ bias, ushort* __restrict__ Y, int ldY, int colTiles)
{
  constexpr int XS = CINP + 8;
  __shared__ ushort XA[64 * XS];
  __shared__ ushort WS[128 * XS];
  int bt = blockIdx.x;
  int row0 = (bt / colTiles) * 64;
  int c0   = (bt % colTiles) * 128;
  int tid = threadIdx.x;
  int lane = tid & 63, wave = tid >> 6;
  int l15 = lane & 15, quad = lane >> 4;
  int wr = wave >> 1, wc = wave & 1;
  constexpr int C8 = CINP/8;

  #pragma unroll
  for (int it = 0; it < CINP/32; it++){
    int idx = tid + it*256;
    int r = idx / C8, c8 = (idx % C8)*8;
    *reinterpret_cast<uint4*>(&XA[r*XS + c8]) =
        *reinterpret_cast<const uint4*>(&X1[(size_t)(row0+r)*CINP + c8]);
  }
  #pragma unroll
  for (int it = 0; it < CINP/16; it++){
    int idx = tid + it*256;
    int n = idx / C8, c8 = (idx % C8)*8;
    *reinterpret_cast<uint4*>(&WS[n*XS + c8]) =
        *reinterpret_cast<const uint4*>(&WT[(size_t)(c0+n)*CINP + c8]);
  }
  __syncthreads();
  ffrag acc[2][4];
  #pragma unroll
  for (int m = 0; m < 2; m++)
    #pragma unroll
    for (int n = 0; n < 4; n++) acc[m][n] = (ffrag){0.f,0.f,0.f,0.f};
  #pragma unroll
  for (int ks = 0; ks < CINP/32; ks++){
    bfrag a[2], b[4];
    #pragma unroll
    for (int m = 0; m < 2; m++)
      a[m] = *reinterpret_cast<const bfrag*>(&XA[(32*wr + 16*m + l15)*XS + ks*32 + quad*8]);
    #pragma unroll
    for (int n = 0; n < 4; n++)
      b[n] = *reinterpret_cast<const bfrag*>(&WS[(64*wc + 16*n + l15)*XS + ks*32 + quad*8]);
    #pragma unroll
    for (int m = 0; m < 2; m++)
      #pragma unroll
      for (int n = 0; n < 4; n++)
        acc[m][n] = __builtin_amdgcn_mfma_f32_16x16x32_bf16(a[m], b[n], acc[m][n], 0, 0, 0);
  }
  #pragma unroll
  for (int m = 0; m < 2; m++)
    #pragma unroll
    for (int n = 0; n < 4; n++){
      int col = c0 + 64*wc + 16*n + l15;
      float bs = bias[col];
      #pragma unroll
      for (int rg = 0; rg < 4; rg++){
        int r = row0 + 32*wr + 16*m + quad*4 + rg;
        Y[(size_t)r*ldY + col] = f2b(acc[m][n][rg] + bs);
      }
    }
}

// ============================================================
// fused GINE MLP: h1 = BN1( relu((h+ag)@g1+b1) @ g2 + b2 + h )
// ============================================================
__global__ __launch_bounds__(256, 2) void gine_mlp(
    const ushort* __restrict__ hb, const ushort* __restrict__ agb,
    const ushort* __restrict__ w1, const float* __restrict__ b1v,
    const ushort* __restrict__ w2, const float* __restrict__ b2v,
    const float* __restrict__ bng, const float* __restrict__ bnb,
    const float* __restrict__ bnm, const float* __restrict__ bnv,
    ushort* __restrict__ h1b)
{
  __shared__ ushort XA[64*136];
  __shared__ ushort WS[128*136];
  __shared__ ushort T1[64*136];
  int row0 = blockIdx.x * 64;
  int tid = threadIdx.x, lane = tid & 63, wave = tid >> 6;
  int l15 = lane & 15, quad = lane >> 4;
  int wr = wave >> 1, wc = wave & 1;

  #pragma unroll
  for (int it = 0; it < 4; it++){
    int idx = tid + it*256;
    int r = idx >> 4, c8 = (idx & 15)*8;
    uint4 av = *reinterpret_cast<const uint4*>(&hb[(size_t)(row0+r)*128 + c8]);
    uint4 bv = *reinterpret_cast<const uint4*>(&agb[(size_t)(row0+r)*128 + c8]);
    uint4 o; o.x=addpair(av.x,bv.x); o.y=addpair(av.y,bv.y); o.z=addpair(av.z,bv.z); o.w=addpair(av.w,bv.w);
    *reinterpret_cast<uint4*>(&XA[r*136 + c8]) = o;
  }
  #pragma unroll
  for (int it = 0; it < 8; it++){
    int idx = tid + it*256;
    int n = idx >> 4, c8 = (idx & 15)*8;
    *reinterpret_cast<uint4*>(&WS[n*136 + c8]) =
        *reinterpret_cast<const uint4*>(&w1[(size_t)n*128 + c8]);
  }
  __syncthreads();
  ffrag acc[2][4];
  #pragma unroll
  for (int m = 0; m < 2; m++)
    #pragma unroll
    for (int n = 0; n < 4; n++) acc[m][n] = (ffrag){0.f,0.f,0.f,0.f};
  #pragma unroll
  for (int ks = 0; ks < 4; ks++){
    bfrag a[2], b[4];
    #pragma unroll
    for (int m = 0; m < 2; m++)
      a[m] = *reinterpret_cast<const bfrag*>(&XA[(32*wr + 16*m + l15)*136 + ks*32 + quad*8]);
    #pragma unroll
    for (int n = 0; n < 4; n++)
      b[n] = *reinterpret_cast<const bfrag*>(&WS[(64*wc + 16*n + l15)*136 + ks*32 + quad*8]);
    #pragma unroll
    for (int m = 0; m < 2; m++)
      #pragma unroll
      for (int n = 0; n < 4; n++)
        acc[m][n] = __builtin_amdgcn_mfma_f32_16x16x32_bf16(a[m], b[n], acc[m][n], 0, 0, 0);
  }
  __syncthreads();
  #pragma unroll
  for (int m = 0; m < 2; m++)
    #pragma unroll
    for (int n = 0; n < 4; n++){
      int col = 64*wc + 16*n + l15;
      float bs = b1v[col];
      #pragma unroll
      for (int rg = 0; rg < 4; rg++){
        int rl = 32*wr + 16*m + quad*4 + rg;
        T1[rl*136 + col] = f2b(fmaxf(acc[m][n][rg] + bs, 0.f));
      }
    }
  #pragma unroll
  for (int it = 0; it < 8; it++){
    int idx = tid + it*256;
    int n = idx >> 4, c8 = (idx & 15)*8;
    *reinterpret_cast<uint4*>(&WS[n*136 + c8]) =
        *reinterpret_cast<const uint4*>(&w2[(size_t)n*128 + c8]);
  }
  __syncthreads();
  #pragma unroll
  for (int m = 0; m < 2; m++)
    #pragma unroll
    for (int n = 0; n < 4; n++) acc[m][n] = (ffrag){0.f,0.f,0.f,0.f};
  #pragma unroll
  for (int ks = 0; ks < 4; ks++){
    bfrag a[2], b[4];
    #pragma unroll
    for (int m = 0; m < 2; m++)
      a[m] = *reinterpret_cast<const bfrag*>(&T1[(32*wr + 16*m + l15)*136 + ks*32 + quad*8]);
    #pragma unroll
    for (int n = 0; n < 4; n++)
      b[n] = *reinterpret_cast<const bfrag*>(&WS[(64*wc + 16*n + l15)*136 + ks*32 + quad*8]);
    #pragma unroll
    for (int m = 0; m < 2; m++)
      #pragma unroll
      for (int n = 0; n < 4; n++)
        acc[m][n] = __builtin_amdgcn_mfma_f32_16x16x32_bf16(a[m], b[n], acc[m][n], 0, 0, 0);
  }
  #pragma unroll
  for (int m = 0; m < 2; m++)
    #pragma unroll
    for (int n = 0; n < 4; n++){
      int col = 64*wc + 16*n + l15;
      float bs = b2v[col];
      float sc = rsqrtf(bnv[col] + 1e-5f) * bng[col];
      float sh = bnb[col] - bnm[col]*sc;
      #pragma unroll
      for (int rg = 0; rg < 4; rg++){
        int r = row0 + 32*wr + 16*m + quad*4 + rg;
        float v = acc[m][n][rg] + bs + b2f(hb[(size_t)r*128 + col]);
        h1b[(size_t)r*128 + col] = f2b(v*sc + sh);
      }
    }
}

// ============================================================
// fused FF tail (out, t2 LDS-resident)
// ============================================================
__global__ __launch_bounds__(256, 1) void ff_fused(
    const ushort* __restrict__ obb, const ushort* __restrict__ hb, const ushort* __restrict__ h1b,
    const ushort* __restrict__ wo, const float* __restrict__ ob_b,
    const float* __restrict__ bn2g, const float* __restrict__ bn2b,
    const float* __restrict__ bn2m, const float* __restrict__ bn2v,
    const ushort* __restrict__ wm1, const float* __restrict__ m1b,
    const ushort* __restrict__ wm2, const float* __restrict__ m2b,
    const float* __restrict__ bn3g, const float* __restrict__ bn3b,
    const float* __restrict__ bn3m, const float* __restrict__ bn3v,
    ushort* __restrict__ hout)
{
  __shared__ ushort XA[64*136];
  __shared__ ushort WS[256*136];
  __shared__ ushort OUT[64*136];
  __shared__ ushort T2[64*264];
  int row0 = blockIdx.x * 64;
  int tid = threadIdx.x, lane = tid & 63, wave = tid >> 6;
  int l15 = lane & 15, quad = lane >> 4;
  int wr = wave >> 1, wc = wave & 1;

  #pragma unroll
  for (int it = 0; it < 4; it++){
    int idx = tid + it*256;
    int r = idx >> 4, c8 = (idx & 15)*8;
    *reinterpret_cast<uint4*>(&XA[r*136 + c8]) =
        *reinterpret_cast<const uint4*>(&obb[(size_t)(row0+r)*128 + c8]);
  }
  #pragma unroll
  for (int it = 0; it < 8; it++){
    int idx = tid + it*256;
    int n = idx >> 4, c8 = (idx & 15)*8;
    *reinterpret_cast<uint4*>(&WS[n*136 + c8]) =
        *reinterpret_cast<const uint4*>(&wo[(size_t)n*128 + c8]);
  }
  __syncthreads();
  ffrag acc[2][4];
  #pragma unroll
  for (int m = 0; m < 2; m++)
    #pragma unroll
    for (int n = 0; n < 4; n++) acc[m][n] = (ffrag){0.f,0.f,0.f,0.f};
  #pragma unroll
  for (int ks = 0; ks < 4; ks++){
    bfrag a[2], b[4];
    #pragma unroll
    for (int m = 0; m < 2; m++)
      a[m] = *reinterpret_cast<const bfrag*>(&XA[(32*wr + 16*m + l15)*136 + ks*32 + quad*8]);
    #pragma unroll
    for (int n = 0; n < 4; n++)
      b[n] = *reinterpret_cast<const bfrag*>(&WS[(64*wc + 16*n + l15)*136 + ks*32 + quad*8]);
    #pragma unroll
    for (int m = 0; m < 2; m++)
      #pragma unroll
      for (int n = 0; n < 4; n++)
        acc[m][n] = __builtin_amdgcn_mfma_f32_16x16x32_bf16(a[m], b[n], acc[m][n], 0, 0, 0);
  }
  __syncthreads();
  #pragma unroll
  for (int m = 0; m < 2; m++)
    #pragma unroll
    for (int n = 0; n < 4; n++){
      int col = 64*wc + 16*n + l15;
      float bs = ob_b[col];
      float sc = rsqrtf(bn2v[col] + 1e-5f) * bn2g[col];
      float sh = bn2b[col] - bn2m[col]*sc;
      #pragma unroll
      for (int rg = 0; rg < 4; rg++){
        int rl = 32*wr + 16*m + quad*4 + rg;
        int r = row0 + rl;
        float v = acc[m][n][rg] + bs + b2f(hb[(size_t)r*128 + col]);
        v = v*sc + sh + b2f(h1b[(size_t)r*128 + col]);
        OUT[rl*136 + col] = f2b(v);
      }
    }
  #pragma unroll
  for (int it = 0; it < 16; it++){
    int idx = tid + it*256;
    int n = idx >> 4, c8 = (idx & 15)*8;
    *reinterpret_cast<uint4*>(&WS[n*136 + c8]) =
        *reinterpret_cast<const uint4*>(&wm1[(size_t)n*128 + c8]);
  }
  __syncthreads();
  ffrag acc2[2][8];
  #pragma unroll
  for (int m = 0; m < 2; m++)
    #pragma unroll
    for (int n = 0; n < 8; n++) acc2[m][n] = (ffrag){0.f,0.f,0.f,0.f};
  #pragma unroll
  for (int ks = 0; ks < 4; ks++){
    bfrag a[2], b[8];
    #pragma unroll
    for (int m = 0; m < 2; m++)
      a[m] = *reinterpret_cast<const bfrag*>(&OUT[(32*wr + 16*m + l15)*136 + ks*32 + quad*8]);
    #pragma unroll
    for (int n = 0; n < 8; n++)
      b[n] = *reinterpret_cast<const bfrag*>(&WS[(128*wc + 16*n + l15)*136 + ks*32 + quad*8]);
    #pragma unroll
    for (int m = 0; m < 2; m++)
      #pragma unroll
      for (int n = 0; n < 8; n++)
        acc2[m][n] = __builtin_amdgcn_mfma_f32_16x16x32_bf16(a[m], b[n], acc2[m][n], 0, 0, 0);
  }
  __syncthreads();
  #pragma unroll
  for (int m = 0; m < 2; m++)
    #pragma unroll
    for (int n = 0; n < 8; n++){
      int col = 128*wc + 16*n + l15;
      float bs = m1b[col];
      #pragma unroll
      for (int rg = 0; rg < 4; rg++){
        int rl = 32*wr + 16*m + quad*4 + rg;
        T2[rl*264 + col] = f2b(fmaxf(acc2[m][n][rg] + bs, 0.f));
      }
    }
  #pragma unroll
  for (int it = 0; it < 16; it++){
    int idx = tid + it*256;
    int n = idx >> 5, c8 = (idx & 31)*8;
    *reinterpret_cast<uint4*>(&WS[n*264 + c8]) =
        *reinterpret_cast<const uint4*>(&wm2[(size_t)n*256 + c8]);
  }
  __syncthreads();
  #pragma unroll
  for (int m = 0; m < 2; m++)
    #pragma unroll
    for (int n = 0; n < 4; n++) acc[m][n] = (ffrag){0.f,0.f,0.f,0.f};
  #pragma unroll
  for (int ks = 0; ks < 8; ks++){
    bfrag a[2], b[4];
    #pragma unroll
    for (int m = 0; m < 2; m++)
      a[m] = *reinterpret_cast<const bfrag*>(&T2[(32*wr + 16*m + l15)*264 + ks*32 + quad*8]);
    #pragma unroll
    for (int n = 0; n < 4; n++)
      b[n] = *reinterpret_cast<const bfrag*>(&WS[(64*wc + 16*n + l15)*264 + ks*32 + quad*8]);
    #pragma unroll
    for (int m = 0; m < 2; m++)
      #pragma unroll
      for (int n = 0; n < 4; n++)
        acc[m][n] = __builtin_amdgcn_mfma_f32_16x16x32_bf16(a[m], b[n], acc[m][n], 0, 0, 0);
  }
  #pragma unroll
  for (int m = 0; m < 2; m++)
    #pragma unroll
    for (int n = 0; n < 4; n++){
      int col = 64*wc + 16*n + l15;
      float bs = m2b[col];
      float sc = rsqrtf(bn3v[col] + 1e-5f) * bn3g[col];
      float sh = bn3b[col] - bn3m[col]*sc;
      #pragma unroll
      for (int rg = 0; rg < 4; rg++){
        int rl = 32*wr + 16*m + quad*4 + rg;
        float v = acc[m][n][rg] + bs + b2f(OUT[rl*136 + col]);
        hout[(size_t)(row0+rl)*128 + col] = f2b(v*sc + sh);
      }
    }
}

// ============================================================
// per-layer collapsed edge weights
// ============================================================
__global__ __launch_bounds__(256) void wp_all(const float* __restrict__ epW, const float* __restrict__ epb,
                                              const float* __restrict__ geW, const float* __restrict__ geb,
                                              float* __restrict__ Wp, float* __restrict__ bp){
  int i = blockIdx.x;
  const float* gw = geW + (size_t)i*16384;
  float* wp = Wp + (size_t)i*1408;
  int tid = threadIdx.x;
  for (int idx = tid; idx < 1408; idx += 256){
    int t = idx >> 7, c = idx & 127;
    float s = 0.f;
    for (int k = 0; k < 128; k++) s += epW[t*128+k] * gw[(size_t)k*128 + c];
    wp[idx] = s;
  }
  if (tid < 128){
    float s = geb[(size_t)i*128 + tid];
    for (int k = 0; k < 128; k++) s += epb[k] * gw[(size_t)k*128 + tid];
    bp[(size_t)i*128 + tid] = s;
  }
}

// ============================================================
// GINE aggregation (node-parallel, bf16 h): high-occupancy version
// ============================================================
__global__ __launch_bounds__(256) void gine_aggr2(const ushort* __restrict__ hb, const float* __restrict__ pk,
                                                  const int* __restrict__ Ecnt,
                                                  const float* __restrict__ Wp, const float* __restrict__ bp,
                                                  ushort* __restrict__ agb){
  int n = blockIdx.x*2 + (threadIdx.x >> 7);
  int ch = threadIdx.x & 127;
  int cnt = Ecnt[n]; if (cnt > 32) cnt = 32;
  float wreg[11];
  #pragma unroll
  for (int t = 0; t < 11; t++) wreg[t] = Wp[t*128 + ch];
  float bpc = bp[ch];
  const float* pkn = pk + (size_t)n*384;
  float acc = 0.f;
  int j = 0;
  for (; j + 4 <= cnt; j += 4){
    const float* p0 = pkn + (size_t)(j+0)*12;
    const float* p1 = pkn + (size_t)(j+1)*12;
    const float* p2 = pkn + (size_t)(j+2)*12;
    const float* p3 = pkn + (size_t)(j+3)*12;
    int s0 = __float_as_int(p0[0]), s1 = __float_as_int(p1[0]);
    int s2 = __float_as_int(p2[0]), s3 = __float_as_int(p3[0]);
    float h0 = b2f(hb[(size_t)s0*128 + ch]);
    float h1 = b2f(hb[(size_t)s1*128 + ch]);
    float h2 = b2f(hb[(size_t)s2*128 + ch]);
    float h3 = b2f(hb[(size_t)s3*128 + ch]);
    float e0 = bpc, e1 = bpc, e2 = bpc, e3 = bpc;
    #pragma unroll
    for (int t = 0; t < 11; t++){
      e0 += p0[1+t]*wreg[t]; e1 += p1[1+t]*wreg[t];
      e2 += p2[1+t]*wreg[t]; e3 += p3[1+t]*wreg[t];
    }
    acc += fmaxf(h0+e0, 0.f) + fmaxf(h1+e1, 0.f) + fmaxf(h2+e2, 0.f) + fmaxf(h3+e3, 0.f);
  }
  for (; j < cnt; j++){
    const float* p0 = pkn + (size_t)j*12;
    int s0 = __float_as_int(p0[0]);
    float h0 = b2f(hb[(size_t)s0*128 + ch]);
    float e0 = bpc;
    #pragma unroll
    for (int t = 0; t < 11; t++) e0 += p0[1+t]*wreg[t];
    acc += fmaxf(h0+e0, 0.f);
  }
  agb[(size_t)n*128 + ch] = f2b(acc);
}

// ============================================================
// MFMA attention
// ============================================================
__global__ __launch_bounds__(256, 2) void attn_mf(const ushort* __restrict__ qkvb, ushort* __restrict__ obb){
  __shared__ ushort Ks[256 * 40];
  __shared__ ushort Vt[32 * 264];
  __shared__ ushort PA[4 * 16 * 264];
  int g = blockIdx.x >> 2, hh = blockIdx.x & 3;
  int tid = threadIdx.x, lane = tid & 63, w = tid >> 6;
  int l15 = lane & 15, quad = lane >> 4;
  const ushort* base = qkvb + (size_t)(g<<8)*384;

  #pragma unroll
  for (int it = 0; it < 4; it++){
    int idx = tid + it*256;
    int key = idx >> 2, d8 = (idx & 3)*8;
    uint4 kv = *reinterpret_cast<const uint4*>(&base[(size_t)key*384 + 128 + hh*32 + d8]);
    *reinterpret_cast<uint4*>(&Ks[key*40 + d8]) = kv;
    uint4 vv = *reinterpret_cast<const uint4*>(&base[(size_t)key*384 + 256 + hh*32 + d8]);
    const ushort* vp = reinterpret_cast<const ushort*>(&vv);
    #pragma unroll
    for (int t = 0; t < 8; t++) Vt[(d8+t)*264 + key] = vp[t];
  }
  bfrag qf[4];
  #pragma unroll
  for (int qg = 0; qg < 4; qg++){
    int q = w*64 + qg*16 + l15;
    qf[qg] = *reinterpret_cast<const bfrag*>(&base[(size_t)q*384 + hh*32 + quad*8]);
  }
  __syncthreads();

  ushort* pw = &PA[w * 16 * 264];
  const float sc_ = 0.17677669529663687f;
  for (int qg = 0; qg < 4; qg++){
    ffrag sc[16];
    #pragma unroll
    for (int kg = 0; kg < 16; kg++){
      bfrag bk = *reinterpret_cast<const bfrag*>(&Ks[(kg*16 + l15)*40 + quad*8]);
      ffrag z = (ffrag){0.f,0.f,0.f,0.f};
      sc[kg] = __builtin_amdgcn_mfma_f32_16x16x32_bf16(qf[qg], bk, z, 0, 0, 0);
    }
    float inv_l[4];
    #pragma unroll
    for (int rg = 0; rg < 4; rg++){
      float m = sc[0][rg];
      #pragma unroll
      for (int kg = 1; kg < 16; kg++) m = fmaxf(m, sc[kg][rg]);
      #pragma unroll
      for (int off = 1; off < 16; off <<= 1) m = fmaxf(m, __shfl_xor(m, off, 16));
      float ssum = 0.f;
      #pragma unroll
      for (int kg = 0; kg < 16; kg++){
        float p = __expf((sc[kg][rg] - m) * sc_);
        sc[kg][rg] = p; ssum += p;
      }
      #pragma unroll
      for (int off = 1; off < 16; off <<= 1) ssum += __shfl_xor(ssum, off, 16);
      inv_l[rg] = 1.f / ssum;
    }
    #pragma unroll
    for (int kg = 0; kg < 16; kg++)
      #pragma unroll
      for (int rg = 0; rg < 4; rg++)
        pw[(quad*4 + rg)*264 + kg*16 + l15] = f2b(sc[kg][rg]);
    ffrag oa[2];
    oa[0] = (ffrag){0.f,0.f,0.f,0.f};
    oa[1] = (ffrag){0.f,0.f,0.f,0.f};
    #pragma unroll
    for (int ks = 0; ks < 8; ks++){
      bfrag pa = *reinterpret_cast<const bfrag*>(&pw[l15*264 + ks*32 + quad*8]);
      #pragma unroll
      for (int n16 = 0; n16 < 2; n16++){
        bfrag bv = *reinterpret_cast<const bfrag*>(&Vt[(n16*16 + l15)*264 + ks*32 + quad*8]);
        oa[n16] = __builtin_amdgcn_mfma_f32_16x16x32_bf16(pa, bv, oa[n16], 0, 0, 0);
      }
    }
    #pragma unroll
    for (int n16 = 0; n16 < 2; n16++)
      #pragma unroll
      for (int rg = 0; rg < 4; rg++){
        int q = w*64 + qg*16 + quad*4 + rg;
        int col = hh*32 + n16*16 + l15;
        obb[((size_t)(g<<8) + q)*128 + col] = f2b(oa[n16][rg] * inv_l[rg]);
      }
  }
}

// ============================================================
// mean-pool + 2-layer head
// ============================================================
__global__ __launch_bounds__(256) void head_kernel(const ushort* __restrict__ hb,
                                                   const float* __restrict__ W1, const float* __restrict__ b1,
                                                   const float* __restrict__ W2, const float* __restrict__ b2,
                                                   float* __restrict__ out){
  int g = blockIdx.x, tid = threadIdx.x;
  int c = tid & 127, half = tid >> 7;
  __shared__ float part[2][128];
  __shared__ float pool[128];
  __shared__ float hid[64];
  float s = 0.f;
  for (int n = half*128; n < half*128 + 128; n++)
    s += b2f(hb[(size_t)((g<<8)+n)*128 + c]);
  part[half][c] = s;
  __syncthreads();
  if (tid < 128) pool[tid] = (part[0][tid] + part[1][tid]) * (1.f/256.f);
  __syncthreads();
  if (tid < 64){
    float v = b1[tid];
    for (int k = 0; k < 128; k++) v += pool[k] * W1[k*64 + tid];
    hid[tid] = fmaxf(v, 0.f);
  }
  __syncthreads();
  if (tid == 0){
    float v = b2[0];
    for (int k = 0; k < 64; k++) v += hid[k] * W2[k];
    out[g] = v;
  }
}

// ============================================================
extern "C" void kernel_launch(void* const* d_in, const int* in_sizes, int n_in,
                              void* d_out, int out_size, void* d_ws, size_t ws_size,
                              hipStream_t stream){
  (void)in_sizes; (void)n_in; (void)out_size; (void)ws_size;
  const float* x      = (const float*)d_in[0];
  const float* eattr  = (const float*)d_in[1];
  const float* in_W   = (const float*)d_in[2];
  const float* in_b   = (const float*)d_in[3];
  const float* ep_W   = (const float*)d_in[4];
  const float* ep_b   = (const float*)d_in[5];
  const float* ge_W   = (const float*)d_in[6];
  const float* ge_b   = (const float*)d_in[7];
  const float* g1_W   = (const float*)d_in[8];
  const float* g1_b   = (const float*)d_in[9];
  const float* g2_W   = (const float*)d_in[10];
  const float* g2_b   = (const float*)d_in[11];
  const float* qkv_W  = (const float*)d_in[12];
  const float* qkv_b  = (const float*)d_in[13];
  const float* o_W    = (const float*)d_in[14];
  const float* o_b    = (const float*)d_in[15];
  const float* bn1g = (const float*)d_in[16]; const float* bn1b = (const float*)d_in[17];
  const float* bn1m = (const float*)d_in[18]; const float* bn1v = (const float*)d_in[19];
  const float* bn2g = (const float*)d_in[20]; const float* bn2b = (const float*)d_in[21];
  const float* bn2m = (const float*)d_in[22]; const float* bn2v = (const float*)d_in[23];
  const float* bn3g = (const float*)d_in[24]; const float* bn3b = (const float*)d_in[25];
  const float* bn3m = (const float*)d_in[26]; const float* bn3v = (const float*)d_in[27];
  const float* m1_W = (const float*)d_in[28]; const float* m1_b = (const float*)d_in[29];
  const float* m2_W = (const float*)d_in[30]; const float* m2_b = (const float*)d_in[31];
  const float* h1_W = (const float*)d_in[32]; const float* h1_b = (const float*)d_in[33];
  const float* h2_W = (const float*)d_in[34]; const float* h2_b = (const float*)d_in[35];
  const int*   ei   = (const int*)d_in[36];
  float* out = (float*)d_out;
  float* ws  = (float*)d_ws;
  int*   wsi = (int*)d_ws;

  // ---- workspace layout (fp32-element offsets) ----
  const size_t oA    = 0;            // 8,388,608  (dead after prep_m2)
  const size_t oMbf  = 8388608;      // 4,194,304  (dead after rwse_mf)
  const size_t oPk   = 12582912;     // 12,582,912
  const size_t oPe   = 25198592;     // 655,360
  const size_t oHb   = 25853952;     // 2,097,152 (bf16 h)
  const size_t oH1b  = 27951104;     // 2,097,152 (bf16 h1)
  const size_t oBb   = 30048256;     // 2,097,152 (bf16 aggr / attn-out)
  const size_t oWp   = 32145408;     // 4,224
  const size_t oBp   = 32149632;     // 384
  const size_t oEcnt = 32412160;     // 32,768
  const size_t oWT   = 32444928;     // 499,712 ushort
  ushort* wt   = (ushort*)(ws + oWT);
  ushort* mbf  = (ushort*)(ws + oMbf);
  ushort* qkvb = (ushort*)(ws + 0);  // overlays A/Mbf region (dead post-RWSE)
  ushort* hb   = (ushort*)(ws + oHb);
  ushort* h1b  = (ushort*)(ws + oH1b);
  ushort* bbuf = (ushort*)(ws + oBb);

  // ---- build + RWSE ----
  hipMemsetAsync(ws + oA, 0, 8388608*sizeof(float), stream);
  hipMemsetAsync(wsi + oEcnt, 0, 32768*sizeof(int), stream);
  build_pack<<<NEDGE/256, 256, 0, stream>>>(ei, eattr, ws+oA, wsi+oEcnt, ws+oPk);
  prep_m2<<<GN, 256, 0, stream>>>(ws+oA, mbf);
  rwse_mf<<<GN*2, 512, 0, stream>>>(mbf, ws+oPe);

  // ---- weight prep ----
  prep_wt<<<dim3(192, 19), 256, 0, stream>>>(in_W, g1_W, g2_W, qkv_W, o_W, m1_W, m2_W, wt);

  // ---- input proj (concat fused) ----
  gemm_in<<<512, 256, 0, stream>>>(x, ws+oPe, wt + 0, in_b, hb);

  wp_all<<<3, 256, 0, stream>>>(ep_W, ep_b, ge_W, ge_b, ws+oWp, ws+oBp);

  // ---- layers ----
  for (int i = 0; i < 3; i++){
    gine_aggr2<<<NN/2, 256, 0, stream>>>(hb, ws+oPk, wsi+oEcnt,
                                         ws+oWp + (size_t)i*1408, ws+oBp + (size_t)i*128, bbuf);
    gine_mlp<<<512, 256, 0, stream>>>(hb, bbuf,
        wt + 8192 + (size_t)i*16384, g1_b + (size_t)i*128,
        wt + 57344 + (size_t)i*16384, g2_b + (size_t)i*128,
        bn1g+(size_t)i*128, bn1b+(size_t)i*128, bn1m+(size_t)i*128, bn1v+(size_t)i*128,
        h1b);
    gemm_b<128><<<1536, 256, 0, stream>>>(hb, wt + 106496 + (size_t)i*49152,
                                          qkv_b + (size_t)i*384, qkvb, 384, 3);
    attn_mf<<<GN*4, 256, 0, stream>>>(qkvb, bbuf);
    ff_fused<<<512, 256, 0, stream>>>(bbuf, hb, h1b,
        wt + 253952 + (size_t)i*16384, o_b + (size_t)i*128,
        bn2g+(size_t)i*128, bn2b+(size_t)i*128, bn2m+(size_t)i*128, bn2v+(size_t)i*128,
        wt + 303104 + (size_t)i*32768, m1_b + (size_t)i*256,
        wt + 401408 + (size_t)i*32768, m2_b + (size_t)i*128,
        bn3g+(size_t)i*128, bn3b+(size_t)i*128, bn3m+(size_t)i*128, bn3v+(size_t)i*128,
        hb);
  }

  head_kernel<<<GN, 256, 0, stream>>>(hb, h1_W, h1_b, h2_W, h2_b, out);
}

// Round 9
// 732.685 us; speedup vs baseline: 1.1457x; 1.1457x over previous
//
#include <hip/hip_runtime.h>

#define GN   128      // graphs
#define GP   256      // nodes per graph
#define NN   32768    // total nodes
#define NEDGE 262144  // total edges
#define WALKN 20

typedef __attribute__((ext_vector_type(8))) short bfrag;   // 8 bf16 (4 VGPRs)
typedef __attribute__((ext_vector_type(4))) float ffrag;   // 4 fp32 acc

__device__ __forceinline__ ushort f2b(float f){
  unsigned u = __float_as_uint(f);
  u += 0x7fffu + ((u >> 16) & 1u);      // RNE
  return (ushort)(u >> 16);
}
__device__ __forceinline__ float b2f(ushort u){
  return __uint_as_float(((unsigned)u) << 16);
}
__device__ __forceinline__ unsigned addpair(unsigned a, unsigned b){
  float alo = __uint_as_float(a << 16), ahi = __uint_as_float(a & 0xffff0000u);
  float blo = __uint_as_float(b << 16), bhi = __uint_as_float(b & 0xffff0000u);
  return ((unsigned)f2b(ahi + bhi) << 16) | (unsigned)f2b(alo + blo);
}

// ============================================================
// build A (dense counts) + pack {src, ea[0..10]} per dst (48B, 32 slots)
// ============================================================
__global__ __launch_bounds__(256) void build_pack(const int* __restrict__ ei, const float* __restrict__ ea,
                                                  float* __restrict__ A, int* __restrict__ Ecnt,
                                                  float* __restrict__ pk){
  int e = blockIdx.x*256 + threadIdx.x;
  int s = ei[e], d = ei[NEDGE + e];
  int g = s >> 8;
  atomicAdd(&A[((size_t)g<<16) + ((size_t)(s&255)<<8) + (size_t)(d&255)], 1.0f);
  int pos = atomicAdd(&Ecnt[d], 1);
  if (pos < 32){
    float* dst = pk + ((size_t)d*32 + pos)*12;
    dst[0] = __int_as_float(s);
    const float* src = ea + (size_t)e*11;
    #pragma unroll
    for (int t = 0; t < 11; t++) dst[1+t] = src[t];
  }
}

// fused: self-loops + out-degree + dense bf16 M[c][r] = A[r][c]/deg[r]
__global__ __launch_bounds__(256) void prep_m2(float* __restrict__ A, ushort* __restrict__ Mbf){
  __shared__ float As[64][65];
  __shared__ float Bs[64][65];
  __shared__ float invd[256];
  int g = blockIdx.x;
  float* Ag = A + ((size_t)g<<16);
  int tid = threadIdx.x, tx = tid & 63, ty = tid >> 6;
  {
    float* row = Ag + ((size_t)tid<<8);
    row[tid] += 1.0f;                       // self loop
    float s = 0.f;
    for (int c = 0; c < 256; c += 4){
      float4 v = *(const float4*)&row[c];
      s += v.x + v.y + v.z + v.w;
    }
    invd[tid] = 1.f / fmaxf(s, 1.0f);
  }
  ushort* Mg = Mbf + ((size_t)g<<16);
  const int pr[10] = {0,0,0,0,1,1,1,2,2,3};
  const int pc[10] = {0,1,2,3,1,2,3,2,3,3};
  for (int t = 0; t < 10; t++){
    int R0 = pr[t]*64, C0 = pc[t]*64;
    __syncthreads();
    #pragma unroll
    for (int i = 0; i < 16; i++){
      As[ty + i*4][tx] = Ag[(size_t)(R0 + ty + i*4)*256 + C0 + tx];
      Bs[ty + i*4][tx] = Ag[(size_t)(C0 + ty + i*4)*256 + R0 + tx];
    }
    __syncthreads();
    #pragma unroll
    for (int i = 0; i < 16; i++){
      int cl = ty + i*4;
      Mg[(size_t)(C0+cl)*256 + R0+tx] = f2b(As[tx][cl] * invd[R0+tx]);
      if (R0 != C0)
        Mg[(size_t)(R0+cl)*256 + C0+tx] = f2b(Bs[tx][cl] * invd[C0+tx]);
    }
  }
}

// ============================================================
// ALL 20 walk steps in one kernel (P^T 64-col slice LDS-resident).
// 256 threads, acc[4][4] -> VGPR 128, no spill (R5-verified, 79 us).
// ============================================================
__global__ __launch_bounds__(256, 2) void rwse_mf(const ushort* __restrict__ Mbf,
                                                  float* __restrict__ pe){
  __shared__ __align__(16) ushort Pt[64*264];
  int bid = blockIdx.x;
  int g  = (bid & 7)*16 + (bid >> 5);
  int cb = ((bid >> 3) & 3) << 6;
  int tid = threadIdx.x, lane = tid & 63, w = tid >> 6;
  int l15 = lane & 15, quad = lane >> 4;
  const ushort* Mg = Mbf + ((size_t)g << 16);
  uint4 z4; z4.x = z4.y = z4.z = z4.w = 0u;
  for (int i = tid; i < 2112; i += 256) reinterpret_cast<uint4*>(Pt)[i] = z4;
  __syncthreads();
  if (tid < 64) Pt[tid*264 + cb + tid] = 0x3F80;
  __syncthreads();

  for (int s = 0; s < WALKN; s++){
    ffrag acc[4][4];
    #pragma unroll
    for (int mi = 0; mi < 4; mi++)
      #pragma unroll
      for (int n = 0; n < 4; n++) acc[mi][n] = (ffrag){0.f,0.f,0.f,0.f};
    for (int k0 = 0; k0 < 256; k0 += 32){
      bfrag a[4], b[4];
      #pragma unroll
      for (int mi = 0; mi < 4; mi++)
        a[mi] = *reinterpret_cast<const bfrag*>(&Mg[(size_t)(w*64 + mi*16 + l15)*256 + k0 + quad*8]);
      #pragma unroll
      for (int n = 0; n < 4; n++)
        b[n] = *reinterpret_cast<const bfrag*>(&Pt[(n*16 + l15)*264 + k0 + quad*8]);
      #pragma unroll
      for (int mi = 0; mi < 4; mi++)
        #pragma unroll
        for (int n = 0; n < 4; n++)
          acc[mi][n] = __builtin_amdgcn_mfma_f32_16x16x32_bf16(a[mi], b[n], acc[mi][n], 0, 0, 0);
    }
    __syncthreads();
    #pragma unroll
    for (int mi = 0; mi < 4; mi++){
      int rbase = w*64 + mi*16 + quad*4;
      #pragma unroll
      for (int n = 0; n < 4; n++){
        int cl = n*16 + l15;
        int dd = cb + cl - rbase;
        if (dd >= 0 && dd < 4){
          float dv = (dd==0)?acc[mi][n][0]:(dd==1)?acc[mi][n][1]:(dd==2)?acc[mi][n][2]:acc[mi][n][3];
          pe[(size_t)((g<<8) + cb + cl)*WALKN + s] = dv;
        }
        ushort4 pkk;
        pkk.x = f2b(acc[mi][n][0]); pkk.y = f2b(acc[mi][n][1]);
        pkk.z = f2b(acc[mi][n][2]); pkk.w = f2b(acc[mi][n][3]);
        *reinterpret_cast<ushort4*>(&Pt[cl*264 + rbase]) = pkk;
      }
    }
    __syncthreads();
  }
}

// ============================================================
// prep: all weights -> bf16 transposed [N][Kp] (B-operand layout)
// ============================================================
__global__ __launch_bounds__(256) void prep_wt(const float* __restrict__ in_W, const float* __restrict__ g1_W,
                                               const float* __restrict__ g2_W, const float* __restrict__ qkv_W,
                                               const float* __restrict__ o_W, const float* __restrict__ m1_W,
                                               const float* __restrict__ m2_W, ushort* __restrict__ wt){
  int rgn = blockIdx.y;
  const float* src; int K, N, Kp; size_t dst;
  if (rgn == 0){ src = in_W; K=50; N=128; Kp=64; dst = 0; }
  else if (rgn <= 3){ int i=rgn-1;  src = g1_W + (size_t)i*16384; K=128; N=128; Kp=128; dst = 8192   + (size_t)i*16384; }
  else if (rgn <= 6){ int i=rgn-4;  src = g2_W + (size_t)i*16384; K=128; N=128; Kp=128; dst = 57344  + (size_t)i*16384; }
  else if (rgn <= 9){ int i=rgn-7;  src = qkv_W+ (size_t)i*49152; K=128; N=384; Kp=128; dst = 106496 + (size_t)i*49152; }
  else if (rgn <= 12){ int i=rgn-10; src = o_W  + (size_t)i*16384; K=128; N=128; Kp=128; dst = 253952 + (size_t)i*16384; }
  else if (rgn <= 15){ int i=rgn-13; src = m1_W + (size_t)i*32768; K=128; N=256; Kp=128; dst = 303104 + (size_t)i*32768; }
  else               { int i=rgn-16; src = m2_W + (size_t)i*32768; K=256; N=128; Kp=256; dst = 401408 + (size_t)i*32768; }
  int sz = N * Kp;
  int idx = blockIdx.x*256 + threadIdx.x;
  if (idx >= sz) return;
  int n = idx / Kp, kp = idx - n*Kp;
  float v = (kp < K) ? src[(size_t)kp*N + n] : 0.f;
  wt[dst + idx] = f2b(v);
}

// ============================================================
// input proj with fused concat: h = [x|pe|0] @ inW + b   (bf16 out)
// ============================================================
__global__ __launch_bounds__(256, 2) void gemm_in(
    const float* __restrict__ x, const float* __restrict__ pe,
    const ushort* __restrict__ WT, const float* __restrict__ bias,
    ushort* __restrict__ Y)
{
  __shared__ ushort XA[64 * 72];
  __shared__ ushort WS[128 * 72];
  int row0 = blockIdx.x * 64;
  int tid = threadIdx.x;
  int lane = tid & 63, wave = tid >> 6;
  int l15 = lane & 15, quad = lane >> 4;
  int wr = wave >> 1, wc = wave & 1;

  #pragma unroll
  for (int it = 0; it < 16; it++){
    int idx = tid + it*256;            // 4096 = 64 rows x 64 cols
    int r = idx >> 6, c = idx & 63;
    float v = 0.f;
    if (c < 30) v = x[(size_t)(row0+r)*30 + c];
    else if (c < 50) v = pe[(size_t)(row0+r)*20 + (c-30)];
    XA[r*72 + c] = f2b(v);
  }
  #pragma unroll
  for (int it = 0; it < 4; it++){
    int idx = tid + it*256;            // 1024 = 128 n x 8 chunks
    int n = idx >> 3, c8 = (idx & 7)*8;
    *reinterpret_cast<uint4*>(&WS[n*72 + c8]) =
        *reinterpret_cast<const uint4*>(&WT[(size_t)n*64 + c8]);
  }
  __syncthreads();
  ffrag acc[2][4];
  #pragma unroll
  for (int m = 0; m < 2; m++)
    #pragma unroll
    for (int n = 0; n < 4; n++) acc[m][n] = (ffrag){0.f,0.f,0.f,0.f};
  #pragma unroll
  for (int ks = 0; ks < 2; ks++){
    bfrag a[2], b[4];
    #pragma unroll
    for (int m = 0; m < 2; m++)
      a[m] = *reinterpret_cast<const bfrag*>(&XA[(32*wr + 16*m + l15)*72 + ks*32 + quad*8]);
    #pragma unroll
    for (int n = 0; n < 4; n++)
      b[n] = *reinterpret_cast<const bfrag*>(&WS[(64*wc + 16*n + l15)*72 + ks*32 + quad*8]);
    #pragma unroll
    for (int m = 0; m < 2; m++)
      #pragma unroll
      for (int n = 0; n < 4; n++)
        acc[m][n] = __builtin_amdgcn_mfma_f32_16x16x32_bf16(a[m], b[n], acc[m][n], 0, 0, 0);
  }
  #pragma unroll
  for (int m = 0; m < 2; m++)
    #pragma unroll
    for (int n = 0; n < 4; n++){
      int col = 64*wc + 16*n + l15;
      float bs = bias[col];
      #pragma unroll
      for (int rg = 0; rg < 4; rg++){
        int r = row0 + 32*wr + 16*m + quad*4 + rg;
        Y[(size_t)r*128 + col] = f2b(acc[m][n][rg] + bs);
      }
    }
}

// ============================================================
// plain bf16 GEMM (bias only): Y[bf16] = X[bf16] @ W + b
// ============================================================
template<int CINP>
__global__ __launch_bounds__(256, 2) void gemm_b(
    const ushort* __restrict__ X1, const ushort* __restrict__ WT,
    const float* __restrict__ bias, ushort* __restrict__ Y, int ldY, int colTiles)
{
  constexpr int XS = CINP + 8;
  __shared__ ushort XA[64 * XS];
  __shared__ ushort WS[128 * XS];
  int bt = blockIdx.x;
  int row0 = (bt / colTiles) * 64;
  int c0   = (bt % colTiles) * 128;
  int tid = threadIdx.x;
  int lane = tid & 63, wave = tid >> 6;
  int l15 = lane & 15, quad = lane >> 4;
  int wr = wave >> 1, wc = wave & 1;
  constexpr int C8 = CINP/8;

  #pragma unroll
  for (int it = 0; it < CINP/32; it++){
    int idx = tid + it*256;
    int r = idx / C8, c8 = (idx % C8)*8;
    *reinterpret_cast<uint4*>(&XA[r*XS + c8]) =
        *reinterpret_cast<const uint4*>(&X1[(size_t)(row0+r)*CINP + c8]);
  }
  #pragma unroll
  for (int it = 0; it < CINP/16; it++){
    int idx = tid + it*256;
    int n = idx / C8, c8 = (idx % C8)*8;
    *reinterpret_cast<uint4*>(&WS[n*XS + c8]) =
        *reinterpret_cast<const uint4*>(&WT[(size_t)(c0+n)*CINP + c8]);
  }
  __syncthreads();
  ffrag acc[2][4];
  #pragma unroll
  for (int m = 0; m < 2; m++)
    #pragma unroll
    for (int n = 0; n < 4; n++) acc[m][n] = (ffrag){0.f,0.f,0.f,0.f};
  #pragma unroll
  for (int ks = 0; ks < CINP/32; ks++){
    bfrag a[2], b[4];
    #pragma unroll
    for (int m = 0; m < 2; m++)
      a[m] = *reinterpret_cast<const bfrag*>(&XA[(32*wr + 16*m + l15)*XS + ks*32 + quad*8]);
    #pragma unroll
    for (int n = 0; n < 4; n++)
      b[n] = *reinterpret_cast<const bfrag*>(&WS[(64*wc + 16*n + l15)*XS + ks*32 + quad*8]);
    #pragma unroll
    for (int m = 0; m < 2; m++)
      #pragma unroll
      for (int n = 0; n < 4; n++)
        acc[m][n] = __builtin_amdgcn_mfma_f32_16x16x32_bf16(a[m], b[n], acc[m][n], 0, 0, 0);
  }
  #pragma unroll
  for (int m = 0; m < 2; m++)
    #pragma unroll
    for (int n = 0; n < 4; n++){
      int col = c0 + 64*wc + 16*n + l15;
      float bs = bias[col];
      #pragma unroll
      for (int rg = 0; rg < 4; rg++){
        int r = row0 + 32*wr + 16*m + quad*4 + rg;
        Y[(size_t)r*ldY + col] = f2b(acc[m][n][rg] + bs);
      }
    }
}

// ============================================================
// fused GINE MLP: h1 = BN1( relu((h+ag)@g1+b1) @ g2 + b2 + h )
// ============================================================
__global__ __launch_bounds__(256, 2) void gine_mlp(
    const ushort* __restrict__ hb, const ushort* __restrict__ agb,
    const ushort* __restrict__ w1, const float* __restrict__ b1v,
    const ushort* __restrict__ w2, const float* __restrict__ b2v,
    const float* __restrict__ bng, const float* __restrict__ bnb,
    const float* __restrict__ bnm, const float* __restrict__ bnv,
    ushort* __restrict__ h1b)
{
  __shared__ ushort XA[64*136];
  __shared__ ushort WS[128*136];
  __shared__ ushort T1[64*136];
  int row0 = blockIdx.x * 64;
  int tid = threadIdx.x, lane = tid & 63, wave = tid >> 6;
  int l15 = lane & 15, quad = lane >> 4;
  int wr = wave >> 1, wc = wave & 1;

  #pragma unroll
  for (int it = 0; it < 4; it++){
    int idx = tid + it*256;
    int r = idx >> 4, c8 = (idx & 15)*8;
    uint4 av = *reinterpret_cast<const uint4*>(&hb[(size_t)(row0+r)*128 + c8]);
    uint4 bv = *reinterpret_cast<const uint4*>(&agb[(size_t)(row0+r)*128 + c8]);
    uint4 o; o.x=addpair(av.x,bv.x); o.y=addpair(av.y,bv.y); o.z=addpair(av.z,bv.z); o.w=addpair(av.w,bv.w);
    *reinterpret_cast<uint4*>(&XA[r*136 + c8]) = o;
  }
  #pragma unroll
  for (int it = 0; it < 8; it++){
    int idx = tid + it*256;
    int n = idx >> 4, c8 = (idx & 15)*8;
    *reinterpret_cast<uint4*>(&WS[n*136 + c8]) =
        *reinterpret_cast<const uint4*>(&w1[(size_t)n*128 + c8]);
  }
  __syncthreads();
  ffrag acc[2][4];
  #pragma unroll
  for (int m = 0; m < 2; m++)
    #pragma unroll
    for (int n = 0; n < 4; n++) acc[m][n] = (ffrag){0.f,0.f,0.f,0.f};
  #pragma unroll
  for (int ks = 0; ks < 4; ks++){
    bfrag a[2], b[4];
    #pragma unroll
    for (int m = 0; m < 2; m++)
      a[m] = *reinterpret_cast<const bfrag*>(&XA[(32*wr + 16*m + l15)*136 + ks*32 + quad*8]);
    #pragma unroll
    for (int n = 0; n < 4; n++)
      b[n] = *reinterpret_cast<const bfrag*>(&WS[(64*wc + 16*n + l15)*136 + ks*32 + quad*8]);
    #pragma unroll
    for (int m = 0; m < 2; m++)
      #pragma unroll
      for (int n = 0; n < 4; n++)
        acc[m][n] = __builtin_amdgcn_mfma_f32_16x16x32_bf16(a[m], b[n], acc[m][n], 0, 0, 0);
  }
  __syncthreads();
  #pragma unroll
  for (int m = 0; m < 2; m++)
    #pragma unroll
    for (int n = 0; n < 4; n++){
      int col = 64*wc + 16*n + l15;
      float bs = b1v[col];
      #pragma unroll
      for (int rg = 0; rg < 4; rg++){
        int rl = 32*wr + 16*m + quad*4 + rg;
        T1[rl*136 + col] = f2b(fmaxf(acc[m][n][rg] + bs, 0.f));
      }
    }
  #pragma unroll
  for (int it = 0; it < 8; it++){
    int idx = tid + it*256;
    int n = idx >> 4, c8 = (idx & 15)*8;
    *reinterpret_cast<uint4*>(&WS[n*136 + c8]) =
        *reinterpret_cast<const uint4*>(&w2[(size_t)n*128 + c8]);
  }
  __syncthreads();
  #pragma unroll
  for (int m = 0; m < 2; m++)
    #pragma unroll
    for (int n = 0; n < 4; n++) acc[m][n] = (ffrag){0.f,0.f,0.f,0.f};
  #pragma unroll
  for (int ks = 0; ks < 4; ks++){
    bfrag a[2], b[4];
    #pragma unroll
    for (int m = 0; m < 2; m++)
      a[m] = *reinterpret_cast<const bfrag*>(&T1[(32*wr + 16*m + l15)*136 + ks*32 + quad*8]);
    #pragma unroll
    for (int n = 0; n < 4; n++)
      b[n] = *reinterpret_cast<const bfrag*>(&WS[(64*wc + 16*n + l15)*136 + ks*32 + quad*8]);
    #pragma unroll
    for (int m = 0; m < 2; m++)
      #pragma unroll
      for (int n = 0; n < 4; n++)
        acc[m][n] = __builtin_amdgcn_mfma_f32_16x16x32_bf16(a[m], b[n], acc[m][n], 0, 0, 0);
  }
  #pragma unroll
  for (int m = 0; m < 2; m++)
    #pragma unroll
    for (int n = 0; n < 4; n++){
      int col = 64*wc + 16*n + l15;
      float bs = b2v[col];
      float sc = rsqrtf(bnv[col] + 1e-5f) * bng[col];
      float sh = bnb[col] - bnm[col]*sc;
      #pragma unroll
      for (int rg = 0; rg < 4; rg++){
        int r = row0 + 32*wr + 16*m + quad*4 + rg;
        float v = acc[m][n][rg] + bs + b2f(hb[(size_t)r*128 + col]);
        h1b[(size_t)r*128 + col] = f2b(v*sc + sh);
      }
    }
}

// ============================================================
// fused FF tail (out, t2 LDS-resident)
// ============================================================
__global__ __launch_bounds__(256, 1) void ff_fused(
    const ushort* __restrict__ obb, const ushort* __restrict__ hb, const ushort* __restrict__ h1b,
    const ushort* __restrict__ wo, const float* __restrict__ ob_b,
    const float* __restrict__ bn2g, const float* __restrict__ bn2b,
    const float* __restrict__ bn2m, const float* __restrict__ bn2v,
    const ushort* __restrict__ wm1, const float* __restrict__ m1b,
    const ushort* __restrict__ wm2, const float* __restrict__ m2b,
    const float* __restrict__ bn3g, const float* __restrict__ bn3b,
    const float* __restrict__ bn3m, const float* __restrict__ bn3v,
    ushort* __restrict__ hout)
{
  __shared__ ushort XA[64*136];
  __shared__ ushort WS[256*136];
  __shared__ ushort OUT[64*136];
  __shared__ ushort T2[64*264];
  int row0 = blockIdx.x * 64;
  int tid = threadIdx.x, lane = tid & 63, wave = tid >> 6;
  int l15 = lane & 15, quad = lane >> 4;
  int wr = wave >> 1, wc = wave & 1;

  #pragma unroll
  for (int it = 0; it < 4; it++){
    int idx = tid + it*256;
    int r = idx >> 4, c8 = (idx & 15)*8;
    *reinterpret_cast<uint4*>(&XA[r*136 + c8]) =
        *reinterpret_cast<const uint4*>(&obb[(size_t)(row0+r)*128 + c8]);
  }
  #pragma unroll
  for (int it = 0; it < 8; it++){
    int idx = tid + it*256;
    int n = idx >> 4, c8 = (idx & 15)*8;
    *reinterpret_cast<uint4*>(&WS[n*136 + c8]) =
        *reinterpret_cast<const uint4*>(&wo[(size_t)n*128 + c8]);
  }
  __syncthreads();
  ffrag acc[2][4];
  #pragma unroll
  for (int m = 0; m < 2; m++)
    #pragma unroll
    for (int n = 0; n < 4; n++) acc[m][n] = (ffrag){0.f,0.f,0.f,0.f};
  #pragma unroll
  for (int ks = 0; ks < 4; ks++){
    bfrag a[2], b[4];
    #pragma unroll
    for (int m = 0; m < 2; m++)
      a[m] = *reinterpret_cast<const bfrag*>(&XA[(32*wr + 16*m + l15)*136 + ks*32 + quad*8]);
    #pragma unroll
    for (int n = 0; n < 4; n++)
      b[n] = *reinterpret_cast<const bfrag*>(&WS[(64*wc + 16*n + l15)*136 + ks*32 + quad*8]);
    #pragma unroll
    for (int m = 0; m < 2; m++)
      #pragma unroll
      for (int n = 0; n < 4; n++)
        acc[m][n] = __builtin_amdgcn_mfma_f32_16x16x32_bf16(a[m], b[n], acc[m][n], 0, 0, 0);
  }
  __syncthreads();
  #pragma unroll
  for (int m = 0; m < 2; m++)
    #pragma unroll
    for (int n = 0; n < 4; n++){
      int col = 64*wc + 16*n + l15;
      float bs = ob_b[col];
      float sc = rsqrtf(bn2v[col] + 1e-5f) * bn2g[col];
      float sh = bn2b[col] - bn2m[col]*sc;
      #pragma unroll
      for (int rg = 0; rg < 4; rg++){
        int rl = 32*wr + 16*m + quad*4 + rg;
        int r = row0 + rl;
        float v = acc[m][n][rg] + bs + b2f(hb[(size_t)r*128 + col]);
        v = v*sc + sh + b2f(h1b[(size_t)r*128 + col]);
        OUT[rl*136 + col] = f2b(v);
      }
    }
  #pragma unroll
  for (int it = 0; it < 16; it++){
    int idx = tid + it*256;
    int n = idx >> 4, c8 = (idx & 15)*8;
    *reinterpret_cast<uint4*>(&WS[n*136 + c8]) =
        *reinterpret_cast<const uint4*>(&wm1[(size_t)n*128 + c8]);
  }
  __syncthreads();
  ffrag acc2[2][8];
  #pragma unroll
  for (int m = 0; m < 2; m++)
    #pragma unroll
    for (int n = 0; n < 8; n++) acc2[m][n] = (ffrag){0.f,0.f,0.f,0.f};
  #pragma unroll
  for (int ks = 0; ks < 4; ks++){
    bfrag a[2], b[8];
    #pragma unroll
    for (int m = 0; m < 2; m++)
      a[m] = *reinterpret_cast<const bfrag*>(&OUT[(32*wr + 16*m + l15)*136 + ks*32 + quad*8]);
    #pragma unroll
    for (int n = 0; n < 8; n++)
      b[n] = *reinterpret_cast<const bfrag*>(&WS[(128*wc + 16*n + l15)*136 + ks*32 + quad*8]);
    #pragma unroll
    for (int m = 0; m < 2; m++)
      #pragma unroll
      for (int n = 0; n < 8; n++)
        acc2[m][n] = __builtin_amdgcn_mfma_f32_16x16x32_bf16(a[m], b[n], acc2[m][n], 0, 0, 0);
  }
  __syncthreads();
  #pragma unroll
  for (int m = 0; m < 2; m++)
    #pragma unroll
    for (int n = 0; n < 8; n++){
      int col = 128*wc + 16*n + l15;
      float bs = m1b[col];
      #pragma unroll
      for (int rg = 0; rg < 4; rg++){
        int rl = 32*wr + 16*m + quad*4 + rg;
        T2[rl*264 + col] = f2b(fmaxf(acc2[m][n][rg] + bs, 0.f));
      }
    }
  #pragma unroll
  for (int it = 0; it < 16; it++){
    int idx = tid + it*256;
    int n = idx >> 5, c8 = (idx & 31)*8;
    *reinterpret_cast<uint4*>(&WS[n*264 + c8]) =
        *reinterpret_cast<const uint4*>(&wm2[(size_t)n*256 + c8]);
  }
  __syncthreads();
  #pragma unroll
  for (int m = 0; m < 2; m++)
    #pragma unroll
    for (int n = 0; n < 4; n++) acc[m][n] = (ffrag){0.f,0.f,0.f,0.f};
  #pragma unroll
  for (int ks = 0; ks < 8; ks++){
    bfrag a[2], b[4];
    #pragma unroll
    for (int m = 0; m < 2; m++)
      a[m] = *reinterpret_cast<const bfrag*>(&T2[(32*wr + 16*m + l15)*264 + ks*32 + quad*8]);
    #pragma unroll
    for (int n = 0; n < 4; n++)
      b[n] = *reinterpret_cast<const bfrag*>(&WS[(64*wc + 16*n + l15)*264 + ks*32 + quad*8]);
    #pragma unroll
    for (int m = 0; m < 2; m++)
      #pragma unroll
      for (int n = 0; n < 4; n++)
        acc[m][n] = __builtin_amdgcn_mfma_f32_16x16x32_bf16(a[m], b[n], acc[m][n], 0, 0, 0);
  }
  #pragma unroll
  for (int m = 0; m < 2; m++)
    #pragma unroll
    for (int n = 0; n < 4; n++){
      int col = 64*wc + 16*n + l15;
      float bs = m2b[col];
      float sc = rsqrtf(bn3v[col] + 1e-5f) * bn3g[col];
      float sh = bn3b[col] - bn3m[col]*sc;
      #pragma unroll
      for (int rg = 0; rg < 4; rg++){
        int rl = 32*wr + 16*m + quad*4 + rg;
        float v = acc[m][n][rg] + bs + b2f(OUT[rl*136 + col]);
        hout[(size_t)(row0+rl)*128 + col] = f2b(v*sc + sh);
      }
    }
}

// ============================================================
// per-layer collapsed edge weights
// ============================================================
__global__ __launch_bounds__(256) void wp_all(const float* __restrict__ epW, const float* __restrict__ epb,
                                              const float* __restrict__ geW, const float* __restrict__ geb,
                                              float* __restrict__ Wp, float* __restrict__ bp){
  int i = blockIdx.x;
  const float* gw = geW + (size_t)i*16384;
  float* wp = Wp + (size_t)i*1408;
  int tid = threadIdx.x;
  for (int idx = tid; idx < 1408; idx += 256){
    int t = idx >> 7, c = idx & 127;
    float s = 0.f;
    for (int k = 0; k < 128; k++) s += epW[t*128+k] * gw[(size_t)k*128 + c];
    wp[idx] = s;
  }
  if (tid < 128){
    float s = geb[(size_t)i*128 + tid];
    for (int k = 0; k < 128; k++) s += epb[k] * gw[(size_t)k*128 + tid];
    bp[(size_t)i*128 + tid] = s;
  }
}

// ============================================================
// GINE aggregation (node-parallel, bf16 h): high-occupancy version
// ============================================================
__global__ __launch_bounds__(256) void gine_aggr2(const ushort* __restrict__ hb, const float* __restrict__ pk,
                                                  const int* __restrict__ Ecnt,
                                                  const float* __restrict__ Wp, const float* __restrict__ bp,
                                                  ushort* __restrict__ agb){
  int n = blockIdx.x*2 + (threadIdx.x >> 7);
  int ch = threadIdx.x & 127;
  int cnt = Ecnt[n]; if (cnt > 32) cnt = 32;
  float wreg[11];
  #pragma unroll
  for (int t = 0; t < 11; t++) wreg[t] = Wp[t*128 + ch];
  float bpc = bp[ch];
  const float* pkn = pk + (size_t)n*384;
  float acc = 0.f;
  int j = 0;
  for (; j + 4 <= cnt; j += 4){
    const float* p0 = pkn + (size_t)(j+0)*12;
    const float* p1 = pkn + (size_t)(j+1)*12;
    const float* p2 = pkn + (size_t)(j+2)*12;
    const float* p3 = pkn + (size_t)(j+3)*12;
    int s0 = __float_as_int(p0[0]), s1 = __float_as_int(p1[0]);
    int s2 = __float_as_int(p2[0]), s3 = __float_as_int(p3[0]);
    float h0 = b2f(hb[(size_t)s0*128 + ch]);
    float h1 = b2f(hb[(size_t)s1*128 + ch]);
    float h2 = b2f(hb[(size_t)s2*128 + ch]);
    float h3 = b2f(hb[(size_t)s3*128 + ch]);
    float e0 = bpc, e1 = bpc, e2 = bpc, e3 = bpc;
    #pragma unroll
    for (int t = 0; t < 11; t++){
      e0 += p0[1+t]*wreg[t]; e1 += p1[1+t]*wreg[t];
      e2 += p2[1+t]*wreg[t]; e3 += p3[1+t]*wreg[t];
    }
    acc += fmaxf(h0+e0, 0.f) + fmaxf(h1+e1, 0.f) + fmaxf(h2+e2, 0.f) + fmaxf(h3+e3, 0.f);
  }
  for (; j < cnt; j++){
    const float* p0 = pkn + (size_t)j*12;
    int s0 = __float_as_int(p0[0]);
    float h0 = b2f(hb[(size_t)s0*128 + ch]);
    float e0 = bpc;
    #pragma unroll
    for (int t = 0; t < 11; t++) e0 += p0[1+t]*wreg[t];
    acc += fmaxf(h0+e0, 0.f);
  }
  agb[(size_t)n*128 + ch] = f2b(acc);
}

// ============================================================
// MFMA attention
// ============================================================
__global__ __launch_bounds__(256, 2) void attn_mf(const ushort* __restrict__ qkvb, ushort* __restrict__ obb){
  __shared__ ushort Ks[256 * 40];
  __shared__ ushort Vt[32 * 264];
  __shared__ ushort PA[4 * 16 * 264];
  int g = blockIdx.x >> 2, hh = blockIdx.x & 3;
  int tid = threadIdx.x, lane = tid & 63, w = tid >> 6;
  int l15 = lane & 15, quad = lane >> 4;
  const ushort* base = qkvb + (size_t)(g<<8)*384;

  #pragma unroll
  for (int it = 0; it < 4; it++){
    int idx = tid + it*256;
    int key = idx >> 2, d8 = (idx & 3)*8;
    uint4 kv = *reinterpret_cast<const uint4*>(&base[(size_t)key*384 + 128 + hh*32 + d8]);
    *reinterpret_cast<uint4*>(&Ks[key*40 + d8]) = kv;
    uint4 vv = *reinterpret_cast<const uint4*>(&base[(size_t)key*384 + 256 + hh*32 + d8]);
    const ushort* vp = reinterpret_cast<const ushort*>(&vv);
    #pragma unroll
    for (int t = 0; t < 8; t++) Vt[(d8+t)*264 + key] = vp[t];
  }
  bfrag qf[4];
  #pragma unroll
  for (int qg = 0; qg < 4; qg++){
    int q = w*64 + qg*16 + l15;
    qf[qg] = *reinterpret_cast<const bfrag*>(&base[(size_t)q*384 + hh*32 + quad*8]);
  }
  __syncthreads();

  ushort* pw = &PA[w * 16 * 264];
  const float sc_ = 0.17677669529663687f;
  for (int qg = 0; qg < 4; qg++){
    ffrag sc[16];
    #pragma unroll
    for (int kg = 0; kg < 16; kg++){
      bfrag bk = *reinterpret_cast<const bfrag*>(&Ks[(kg*16 + l15)*40 + quad*8]);
      ffrag z = (ffrag){0.f,0.f,0.f,0.f};
      sc[kg] = __builtin_amdgcn_mfma_f32_16x16x32_bf16(qf[qg], bk, z, 0, 0, 0);
    }
    float inv_l[4];
    #pragma unroll
    for (int rg = 0; rg < 4; rg++){
      float m = sc[0][rg];
      #pragma unroll
      for (int kg = 1; kg < 16; kg++) m = fmaxf(m, sc[kg][rg]);
      #pragma unroll
      for (int off = 1; off < 16; off <<= 1) m = fmaxf(m, __shfl_xor(m, off, 16));
      float ssum = 0.f;
      #pragma unroll
      for (int kg = 0; kg < 16; kg++){
        float p = __expf((sc[kg][rg] - m) * sc_);
        sc[kg][rg] = p; ssum += p;
      }
      #pragma unroll
      for (int off = 1; off < 16; off <<= 1) ssum += __shfl_xor(ssum, off, 16);
      inv_l[rg] = 1.f / ssum;
    }
    #pragma unroll
    for (int kg = 0; kg < 16; kg++)
      #pragma unroll
      for (int rg = 0; rg < 4; rg++)
        pw[(quad*4 + rg)*264 + kg*16 + l15] = f2b(sc[kg][rg]);
    ffrag oa[2];
    oa[0] = (ffrag){0.f,0.f,0.f,0.f};
    oa[1] = (ffrag){0.f,0.f,0.f,0.f};
    #pragma unroll
    for (int ks = 0; ks < 8; ks++){
      bfrag pa = *reinterpret_cast<const bfrag*>(&pw[l15*264 + ks*32 + quad*8]);
      #pragma unroll
      for (int n16 = 0; n16 < 2; n16++){
        bfrag bv = *reinterpret_cast<const bfrag*>(&Vt[(n16*16 + l15)*264 + ks*32 + quad*8]);
        oa[n16] = __builtin_amdgcn_mfma_f32_16x16x32_bf16(pa, bv, oa[n16], 0, 0, 0);
      }
    }
    #pragma unroll
    for (int n16 = 0; n16 < 2; n16++)
      #pragma unroll
      for (int rg = 0; rg < 4; rg++){
        int q = w*64 + qg*16 + quad*4 + rg;
        int col = hh*32 + n16*16 + l15;
        obb[((size_t)(g<<8) + q)*128 + col] = f2b(oa[n16][rg] * inv_l[rg]);
      }
  }
}

// ============================================================
// mean-pool + 2-layer head
// ============================================================
__global__ __launch_bounds__(256) void head_kernel(const ushort* __restrict__ hb,
                                                   const float* __restrict__ W1, const float* __restrict__ b1,
                                                   const float* __restrict__ W2, const float* __restrict__ b2,
                                                   float* __restrict__ out){
  int g = blockIdx.x, tid = threadIdx.x;
  int c = tid & 127, half = tid >> 7;
  __shared__ float part[2][128];
  __shared__ float pool[128];
  __shared__ float hid[64];
  float s = 0.f;
  for (int n = half*128; n < half*128 + 128; n++)
    s += b2f(hb[(size_t)((g<<8)+n)*128 + c]);
  part[half][c] = s;
  __syncthreads();
  if (tid < 128) pool[tid] = (part[0][tid] + part[1][tid]) * (1.f/256.f);
  __syncthreads();
  if (tid < 64){
    float v = b1[tid];
    for (int k = 0; k < 128; k++) v += pool[k] * W1[k*64 + tid];
    hid[tid] = fmaxf(v, 0.f);
  }
  __syncthreads();
  if (tid == 0){
    float v = b2[0];
    for (int k = 0; k < 64; k++) v += hid[k] * W2[k];
    out[g] = v;
  }
}

// ============================================================
extern "C" void kernel_launch(void* const* d_in, const int* in_sizes, int n_in,
                              void* d_out, int out_size, void* d_ws, size_t ws_size,
                              hipStream_t stream){
  (void)in_sizes; (void)n_in; (void)out_size; (void)ws_size;
  const float* x      = (const float*)d_in[0];
  const float* eattr  = (const float*)d_in[1];
  const float* in_W   = (const float*)d_in[2];
  const float* in_b   = (const float*)d_in[3];
  const float* ep_W   = (const float*)d_in[4];
  const float* ep_b   = (const float*)d_in[5];
  const float* ge_W   = (const float*)d_in[6];
  const float* ge_b   = (const float*)d_in[7];
  const float* g1_W   = (const float*)d_in[8];
  const float* g1_b   = (const float*)d_in[9];
  const float* g2_W   = (const float*)d_in[10];
  const float* g2_b   = (const float*)d_in[11];
  const float* qkv_W  = (const float*)d_in[12];
  const float* qkv_b  = (const float*)d_in[13];
  const float* o_W    = (const float*)d_in[14];
  const float* o_b    = (const float*)d_in[15];
  const float* bn1g = (const float*)d_in[16]; const float* bn1b = (const float*)d_in[17];
  const float* bn1m = (const float*)d_in[18]; const float* bn1v = (const float*)d_in[19];
  const float* bn2g = (const float*)d_in[20]; const float* bn2b = (const float*)d_in[21];
  const float* bn2m = (const float*)d_in[22]; const float* bn2v = (const float*)d_in[23];
  const float* bn3g = (const float*)d_in[24]; const float* bn3b = (const float*)d_in[25];
  const float* bn3m = (const float*)d_in[26]; const float* bn3v = (const float*)d_in[27];
  const float* m1_W = (const float*)d_in[28]; const float* m1_b = (const float*)d_in[29];
  const float* m2_W = (const float*)d_in[30]; const float* m2_b = (const float*)d_in[31];
  const float* h1_W = (const float*)d_in[32]; const float* h1_b = (const float*)d_in[33];
  const float* h2_W = (const float*)d_in[34]; const float* h2_b = (const float*)d_in[35];
  const int*   ei   = (const int*)d_in[36];
  float* out = (float*)d_out;
  float* ws  = (float*)d_ws;
  int*   wsi = (int*)d_ws;

  // ---- workspace layout (fp32-element offsets) ----
  const size_t oA    = 0;            // 8,388,608  (dead after prep_m2)
  const size_t oMbf  = 8388608;      // 4,194,304  (dead after rwse_mf)
  const size_t oPk   = 12582912;     // 12,582,912
  const size_t oPe   = 25198592;     // 655,360
  const size_t oHb   = 25853952;     // 2,097,152 (bf16 h)
  const size_t oH1b  = 27951104;     // 2,097,152 (bf16 h1)
  const size_t oBb   = 30048256;     // 2,097,152 (bf16 aggr / attn-out)
  const size_t oWp   = 32145408;     // 4,224
  const size_t oBp   = 32149632;     // 384
  const size_t oEcnt = 32412160;     // 32,768
  const size_t oWT   = 32444928;     // 499,712 ushort
  ushort* wt   = (ushort*)(ws + oWT);
  ushort* mbf  = (ushort*)(ws + oMbf);
  ushort* qkvb = (ushort*)(ws + 0);  // overlays A/Mbf region (dead post-RWSE)
  ushort* hb   = (ushort*)(ws + oHb);
  ushort* h1b  = (ushort*)(ws + oH1b);
  ushort* bbuf = (ushort*)(ws + oBb);

  // ---- build + RWSE ----
  hipMemsetAsync(ws + oA, 0, 8388608*sizeof(float), stream);
  hipMemsetAsync(wsi + oEcnt, 0, 32768*sizeof(int), stream);
  build_pack<<<NEDGE/256, 256, 0, stream>>>(ei, eattr, ws+oA, wsi+oEcnt, ws+oPk);
  prep_m2<<<GN, 256, 0, stream>>>(ws+oA, mbf);
  rwse_mf<<<GN*4, 256, 0, stream>>>(mbf, ws+oPe);

  // ---- weight prep ----
  prep_wt<<<dim3(192, 19), 256, 0, stream>>>(in_W, g1_W, g2_W, qkv_W, o_W, m1_W, m2_W, wt);

  // ---- input proj (concat fused) ----
  gemm_in<<<512, 256, 0, stream>>>(x, ws+oPe, wt + 0, in_b, hb);

  wp_all<<<3, 256, 0, stream>>>(ep_W, ep_b, ge_W, ge_b, ws+oWp, ws+oBp);

  // ---- layers ----
  for (int i = 0; i < 3; i++){
    gine_aggr2<<<NN/2, 256, 0, stream>>>(hb, ws+oPk, wsi+oEcnt,
                                         ws+oWp + (size_t)i*1408, ws+oBp + (size_t)i*128, bbuf);
    gine_mlp<<<512, 256, 0, stream>>>(hb, bbuf,
        wt + 8192 + (size_t)i*16384, g1_b + (size_t)i*128,
        wt + 57344 + (size_t)i*16384, g2_b + (size_t)i*128,
        bn1g+(size_t)i*128, bn1b+(size_t)i*128, bn1m+(size_t)i*128, bn1v+(size_t)i*128,
        h1b);
    gemm_b<128><<<1536, 256, 0, stream>>>(hb, wt + 106496 + (size_t)i*49152,
                                          qkv_b + (size_t)i*384, qkvb, 384, 3);
    attn_mf<<<GN*4, 256, 0, stream>>>(qkvb, bbuf);
    ff_fused<<<512, 256, 0, stream>>>(bbuf, hb, h1b,
        wt + 253952 + (size_t)i*16384, o_b + (size_t)i*128,
        bn2g+(size_t)i*128, bn2b+(size_t)i*128, bn2m+(size_t)i*128, bn2v+(size_t)i*128,
        wt + 303104 + (size_t)i*32768, m1_b + (size_t)i*256,
        wt + 401408 + (size_t)i*32768, m2_b + (size_t)i*128,
        bn3g+(size_t)i*128, bn3b+(size_t)i*128, bn3m+(size_t)i*128, bn3v+(size_t)i*128,
        hb);
  }

  head_kernel<<<GN, 256, 0, stream>>>(hb, h1_W, h1_b, h2_W, h2_b, out);
}